// Round 3
// baseline (2936.872 us; speedup 1.0000x reference)
//
#include <hip/hip_runtime.h>

#define N_NODES 100000
#define N_EDGES 1600000
#define D 128

#define FMA4(A, S, W) do { (A).x += (S)*(W).x; (A).y += (S)*(W).y; (A).z += (S)*(W).z; (A).w += (S)*(W).w; } while(0)

// Degree scratch lives in the module's device data segment -> no reliance on d_ws.
__device__ float g_deg[N_NODES];

// Zero out[] (as float4) and g_deg[]. Replaces hipMemsetAsync (graph-capture safe by construction).
__global__ __launch_bounds__(256) void sag_init(float* __restrict__ out)
{
    const int tid = blockIdx.x * 256 + threadIdx.x;
    const int stride = gridDim.x * 256;
    float4* o4 = reinterpret_cast<float4*>(out);
    const int n4 = N_NODES * D / 4;   // 3.2M float4
    for (int i = tid; i < n4; i += stride)
        o4[i] = make_float4(0.f, 0.f, 0.f, 0.f);
    for (int i = tid; i < N_NODES; i += stride)
        g_deg[i] = 0.f;
}

// Scatter: acc[dst] += x[src] (f32 atomics), g_deg[dst] += 1.
// edge_index arrives as int32 (harness converts integer inputs to int32).
// 32 lanes per edge, each lane handles 4 consecutive floats (float4 gather).
__global__ __launch_bounds__(256) void sag_scatter(
    const float* __restrict__ x,
    const int* __restrict__ ei,
    float* __restrict__ acc)
{
    int g = blockIdx.x * 256 + threadIdx.x;
    int e = g >> 5;
    if (e >= N_EDGES) return;
    int lane = g & 31;
    int src = ei[e];
    int dst = ei[N_EDGES + e];
    float4 v = *reinterpret_cast<const float4*>(x + src * D + lane * 4);
    float* p = acc + dst * D + lane * 4;
    atomicAdd(p + 0, v.x);
    atomicAdd(p + 1, v.y);
    atomicAdd(p + 2, v.z);
    atomicAdd(p + 3, v.w);
    if (lane == 0) atomicAdd(&g_deg[dst], 1.0f);
}

// Fused GEMM: out[n] = x[n]@Ws + a[n]@Wn + bias, where
// a[n] = acc[n]/deg[n] - x[n] (deg>0) else 0.  acc lives in `out` on entry.
// Block: 32 nodes (3125 blocks exactly cover 100000 nodes -> no bounds checks).
// LDS: 4 x 16KB = 64KB -> 2 blocks/CU.
// Thread (cg=t&31, ns=t>>5): 4 nodes (ns*4..ns*4+3) x 4 cols (cg*4..cg*4+3).
__global__ __launch_bounds__(256) void sag_gemm(
    const float* __restrict__ x,
    const float* __restrict__ Ws,
    const float* __restrict__ Wn,
    const float* __restrict__ bias,
    float* __restrict__ out)
{
    __shared__ float lx[32][D];
    __shared__ float la[32][D];
    __shared__ float lws[32][D];
    __shared__ float lwn[32][D];

    const int t = threadIdx.x;
    const int nb = blockIdx.x * 32;

    // Stage x rows and a = acc/deg - x rows into LDS. 1024 float4, 4 per thread.
    #pragma unroll
    for (int i = 0; i < 4; ++i) {
        int f = t + i * 256;      // float4 index (32 rows x 32 f4)
        int row = f >> 5;
        int c4 = f & 31;
        int n = nb + row;
        float4 xv = *reinterpret_cast<const float4*>(x + n * D + c4 * 4);
        float4 av = make_float4(0.f, 0.f, 0.f, 0.f);
        float dg = g_deg[n];
        if (dg > 0.f) {
            float inv = 1.f / dg;
            float4 ac = *reinterpret_cast<const float4*>(out + n * D + c4 * 4);
            av.x = ac.x * inv - xv.x;
            av.y = ac.y * inv - xv.y;
            av.z = ac.z * inv - xv.z;
            av.w = ac.w * inv - xv.w;
        }
        *reinterpret_cast<float4*>(&lx[row][c4 * 4]) = xv;
        *reinterpret_cast<float4*>(&la[row][c4 * 4]) = av;
    }

    const int cg = t & 31;
    const int ns = t >> 5;

    float4 acc[4];
    #pragma unroll
    for (int i = 0; i < 4; ++i) acc[i] = make_float4(0.f, 0.f, 0.f, 0.f);

    for (int kc = 0; kc < 4; ++kc) {
        __syncthreads();   // covers x/a staging (kc=0) and lws/lwn reuse (kc>0)
        // Stage W chunk rows kc*32 .. kc*32+31 for both matrices.
        #pragma unroll
        for (int i = 0; i < 4; ++i) {
            int f = t + i * 256;   // 1024 float4 per matrix chunk
            int row = f >> 5;
            int c4 = f & 31;
            *reinterpret_cast<float4*>(&lws[row][c4 * 4]) =
                *reinterpret_cast<const float4*>(Ws + (kc * 32 + row) * D + c4 * 4);
            *reinterpret_cast<float4*>(&lwn[row][c4 * 4]) =
                *reinterpret_cast<const float4*>(Wn + (kc * 32 + row) * D + c4 * 4);
        }
        __syncthreads();

        #pragma unroll
        for (int kk4 = 0; kk4 < 8; ++kk4) {
            const int k0 = kk4 * 4;
            float4 ws0 = *reinterpret_cast<const float4*>(&lws[k0 + 0][cg * 4]);
            float4 ws1 = *reinterpret_cast<const float4*>(&lws[k0 + 1][cg * 4]);
            float4 ws2 = *reinterpret_cast<const float4*>(&lws[k0 + 2][cg * 4]);
            float4 ws3 = *reinterpret_cast<const float4*>(&lws[k0 + 3][cg * 4]);
            float4 wn0 = *reinterpret_cast<const float4*>(&lwn[k0 + 0][cg * 4]);
            float4 wn1 = *reinterpret_cast<const float4*>(&lwn[k0 + 1][cg * 4]);
            float4 wn2 = *reinterpret_cast<const float4*>(&lwn[k0 + 2][cg * 4]);
            float4 wn3 = *reinterpret_cast<const float4*>(&lwn[k0 + 3][cg * 4]);
            #pragma unroll
            for (int i = 0; i < 4; ++i) {
                int nl = ns * 4 + i;
                float4 xv = *reinterpret_cast<const float4*>(&lx[nl][kc * 32 + k0]);
                float4 av = *reinterpret_cast<const float4*>(&la[nl][kc * 32 + k0]);
                FMA4(acc[i], xv.x, ws0);
                FMA4(acc[i], xv.y, ws1);
                FMA4(acc[i], xv.z, ws2);
                FMA4(acc[i], xv.w, ws3);
                FMA4(acc[i], av.x, wn0);
                FMA4(acc[i], av.y, wn1);
                FMA4(acc[i], av.z, wn2);
                FMA4(acc[i], av.w, wn3);
            }
        }
    }

    float4 b = *reinterpret_cast<const float4*>(bias + cg * 4);
    #pragma unroll
    for (int i = 0; i < 4; ++i) {
        int n = nb + ns * 4 + i;
        float4 r;
        r.x = acc[i].x + b.x;
        r.y = acc[i].y + b.y;
        r.z = acc[i].z + b.z;
        r.w = acc[i].w + b.w;
        *reinterpret_cast<float4*>(out + n * D + cg * 4) = r;
    }
}

extern "C" void kernel_launch(void* const* d_in, const int* in_sizes, int n_in,
                              void* d_out, int out_size, void* d_ws, size_t ws_size,
                              hipStream_t stream) {
    const float* x     = (const float*)d_in[0];
    const int* ei      = (const int*)d_in[1];     // int inputs arrive as int32
    const float* Ws    = (const float*)d_in[2];
    const float* Wn    = (const float*)d_in[3];
    const float* bias  = (const float*)d_in[4];
    float* out = (float*)d_out;

    sag_init<<<2048, 256, 0, stream>>>(out);

    const int scatter_blocks = (N_EDGES * 32) / 256;  // 200000
    sag_scatter<<<scatter_blocks, 256, 0, stream>>>(x, ei, out);

    const int gemm_blocks = N_NODES / 32;             // 3125
    sag_gemm<<<gemm_blocks, 256, 0, stream>>>(x, Ws, Wn, bias, out);
}

// Round 4
// 471.562 us; speedup vs baseline: 6.2280x; 6.2280x over previous
//
#include <hip/hip_runtime.h>

#define N_NODES 100000
#define N_EDGES 1600000
#define D 128

#define FMA4(A, S, W) do { (A).x += (S)*(W).x; (A).y += (S)*(W).y; (A).z += (S)*(W).z; (A).w += (S)*(W).w; } while(0)

// ---- CSR scratch in the module's device data segment (no d_ws dependency) ----
#define NB_SCAN 98   // ceil(100000/1024)
__device__ int g_hist[N_NODES];
__device__ int g_rowptr[N_NODES + 1];
__device__ int g_cursor[N_NODES];
__device__ int g_bsum[NB_SCAN];
__device__ int g_boff[NB_SCAN];
__device__ int g_csr[N_EDGES];

// Zero the degree histogram (must re-zero every call; harness doesn't re-poison).
__global__ __launch_bounds__(256) void csr_zero()
{
    int i = blockIdx.x * 256 + threadIdx.x;
    if (i < N_NODES) g_hist[i] = 0;
}

// In-degree histogram: 1.6M int atomics on an L2-resident 400KB table.
__global__ __launch_bounds__(256) void csr_hist(const int* __restrict__ ei)
{
    int e = blockIdx.x * 256 + threadIdx.x;
    if (e < N_EDGES) atomicAdd(&g_hist[ei[N_EDGES + e]], 1);
}

// Scan pass A: per-block (1024 elems) local exclusive scan + block total.
__global__ __launch_bounds__(256) void csr_scanA()
{
    __shared__ int lds[256];
    const int b = blockIdx.x, t = threadIdx.x;
    const int base = b * 1024 + t * 4;
    int v0 = (base + 0 < N_NODES) ? g_hist[base + 0] : 0;
    int v1 = (base + 1 < N_NODES) ? g_hist[base + 1] : 0;
    int v2 = (base + 2 < N_NODES) ? g_hist[base + 2] : 0;
    int v3 = (base + 3 < N_NODES) ? g_hist[base + 3] : 0;
    const int s = v0 + v1 + v2 + v3;
    lds[t] = s;
    __syncthreads();
    for (int off = 1; off < 256; off <<= 1) {
        int add = (t >= off) ? lds[t - off] : 0;
        __syncthreads();
        lds[t] += add;
        __syncthreads();
    }
    int e = lds[t] - s;   // exclusive block-local offset
    if (base + 0 < N_NODES) g_rowptr[base + 0] = e;           e += v0;
    if (base + 1 < N_NODES) g_rowptr[base + 1] = e;           e += v1;
    if (base + 2 < N_NODES) g_rowptr[base + 2] = e;           e += v2;
    if (base + 3 < N_NODES) g_rowptr[base + 3] = e;
    if (t == 255) g_bsum[b] = lds[255];
}

// Scan pass B: serial scan of 98 block sums (trivial).
__global__ __launch_bounds__(64) void csr_scanB()
{
    if (threadIdx.x == 0 && blockIdx.x == 0) {
        int run = 0;
        for (int b = 0; b < NB_SCAN; ++b) { g_boff[b] = run; run += g_bsum[b]; }
        g_rowptr[N_NODES] = run;   // == N_EDGES
    }
}

// Scan pass C: add block offsets; init cursors.
__global__ __launch_bounds__(256) void csr_scanC()
{
    const int b = blockIdx.x, t = threadIdx.x;
    const int base = b * 1024 + t * 4;
    const int off = g_boff[b];
    #pragma unroll
    for (int k = 0; k < 4; ++k) {
        int i = base + k;
        if (i < N_NODES) {
            int r = g_rowptr[i] + off;
            g_rowptr[i] = r;
            g_cursor[i] = r;
        }
    }
}

// Fill CSR src lists via atomic cursor.
__global__ __launch_bounds__(256) void csr_fill(const int* __restrict__ ei)
{
    int e = blockIdx.x * 256 + threadIdx.x;
    if (e < N_EDGES) {
        int dst = ei[N_EDGES + e];
        int pos = atomicAdd(&g_cursor[dst], 1);
        g_csr[pos] = ei[e];   // src
    }
}

// Pull-gather: a[n] = (sum_{src in N(n)} x[src]) / deg - x[n]  (0 if deg==0).
// 32 lanes per node, float4 per lane; 8 nodes per 256-thread block.
__global__ __launch_bounds__(256) void sag_gather(
    const float* __restrict__ x,
    float* __restrict__ a)
{
    const int g = blockIdx.x * 256 + threadIdx.x;
    const int node = g >> 5;           // grid covers exactly 100000 nodes
    const int lane = g & 31;
    const int beg = g_rowptr[node];
    const int end = g_rowptr[node + 1];
    const int deg = end - beg;
    const float4* __restrict__ x4 = reinterpret_cast<const float4*>(x);

    float4 acc = make_float4(0.f, 0.f, 0.f, 0.f);
    for (int base = beg; base < end; base += 32) {
        const int cnt = min(32, end - base);
        int sid = 0;
        if (lane < cnt) sid = g_csr[base + lane];
        int j = 0;
        for (; j + 8 <= cnt; j += 8) {
            int s0 = __shfl(sid, j + 0, 32);
            int s1 = __shfl(sid, j + 1, 32);
            int s2 = __shfl(sid, j + 2, 32);
            int s3 = __shfl(sid, j + 3, 32);
            int s4 = __shfl(sid, j + 4, 32);
            int s5 = __shfl(sid, j + 5, 32);
            int s6 = __shfl(sid, j + 6, 32);
            int s7 = __shfl(sid, j + 7, 32);
            float4 v0 = x4[s0 * 32 + lane];
            float4 v1 = x4[s1 * 32 + lane];
            float4 v2 = x4[s2 * 32 + lane];
            float4 v3 = x4[s3 * 32 + lane];
            float4 v4 = x4[s4 * 32 + lane];
            float4 v5 = x4[s5 * 32 + lane];
            float4 v6 = x4[s6 * 32 + lane];
            float4 v7 = x4[s7 * 32 + lane];
            acc.x += v0.x; acc.y += v0.y; acc.z += v0.z; acc.w += v0.w;
            acc.x += v1.x; acc.y += v1.y; acc.z += v1.z; acc.w += v1.w;
            acc.x += v2.x; acc.y += v2.y; acc.z += v2.z; acc.w += v2.w;
            acc.x += v3.x; acc.y += v3.y; acc.z += v3.z; acc.w += v3.w;
            acc.x += v4.x; acc.y += v4.y; acc.z += v4.z; acc.w += v4.w;
            acc.x += v5.x; acc.y += v5.y; acc.z += v5.z; acc.w += v5.w;
            acc.x += v6.x; acc.y += v6.y; acc.z += v6.z; acc.w += v6.w;
            acc.x += v7.x; acc.y += v7.y; acc.z += v7.z; acc.w += v7.w;
        }
        for (; j < cnt; ++j) {
            int s = __shfl(sid, j, 32);
            float4 v = x4[s * 32 + lane];
            acc.x += v.x; acc.y += v.y; acc.z += v.z; acc.w += v.w;
        }
    }

    float4 r = make_float4(0.f, 0.f, 0.f, 0.f);
    if (deg > 0) {
        const float inv = 1.f / (float)deg;
        const float4 xv = x4[node * 32 + lane];
        r.x = acc.x * inv - xv.x;
        r.y = acc.y * inv - xv.y;
        r.z = acc.z * inv - xv.z;
        r.w = acc.w * inv - xv.w;
    }
    reinterpret_cast<float4*>(a)[node * 32 + lane] = r;
}

// Fused GEMM: out[n] = x[n]@Ws + a[n]@Wn + bias.  `a` lives in `out` on entry.
// Block: 32 nodes (3125 blocks exactly cover 100000 nodes).
// LDS: 4 x 16KB = 64KB -> 2 blocks/CU.
__global__ __launch_bounds__(256) void sag_gemm(
    const float* __restrict__ x,
    const float* __restrict__ Ws,
    const float* __restrict__ Wn,
    const float* __restrict__ bias,
    float* __restrict__ out)
{
    __shared__ float lx[32][D];
    __shared__ float la[32][D];
    __shared__ float lws[32][D];
    __shared__ float lwn[32][D];

    const int t = threadIdx.x;
    const int nb = blockIdx.x * 32;

    // Stage x rows and a rows into LDS. 1024 float4, 4 per thread.
    #pragma unroll
    for (int i = 0; i < 4; ++i) {
        int f = t + i * 256;      // float4 index (32 rows x 32 f4)
        int row = f >> 5;
        int c4 = f & 31;
        int n = nb + row;
        float4 xv = *reinterpret_cast<const float4*>(x + n * D + c4 * 4);
        float4 av = *reinterpret_cast<const float4*>(out + n * D + c4 * 4);
        *reinterpret_cast<float4*>(&lx[row][c4 * 4]) = xv;
        *reinterpret_cast<float4*>(&la[row][c4 * 4]) = av;
    }

    const int cg = t & 31;
    const int ns = t >> 5;

    float4 acc[4];
    #pragma unroll
    for (int i = 0; i < 4; ++i) acc[i] = make_float4(0.f, 0.f, 0.f, 0.f);

    for (int kc = 0; kc < 4; ++kc) {
        __syncthreads();   // covers x/a staging (kc=0) and lws/lwn reuse (kc>0)
        #pragma unroll
        for (int i = 0; i < 4; ++i) {
            int f = t + i * 256;   // 1024 float4 per matrix chunk
            int row = f >> 5;
            int c4 = f & 31;
            *reinterpret_cast<float4*>(&lws[row][c4 * 4]) =
                *reinterpret_cast<const float4*>(Ws + (kc * 32 + row) * D + c4 * 4);
            *reinterpret_cast<float4*>(&lwn[row][c4 * 4]) =
                *reinterpret_cast<const float4*>(Wn + (kc * 32 + row) * D + c4 * 4);
        }
        __syncthreads();

        #pragma unroll
        for (int kk4 = 0; kk4 < 8; ++kk4) {
            const int k0 = kk4 * 4;
            float4 ws0 = *reinterpret_cast<const float4*>(&lws[k0 + 0][cg * 4]);
            float4 ws1 = *reinterpret_cast<const float4*>(&lws[k0 + 1][cg * 4]);
            float4 ws2 = *reinterpret_cast<const float4*>(&lws[k0 + 2][cg * 4]);
            float4 ws3 = *reinterpret_cast<const float4*>(&lws[k0 + 3][cg * 4]);
            float4 wn0 = *reinterpret_cast<const float4*>(&lwn[k0 + 0][cg * 4]);
            float4 wn1 = *reinterpret_cast<const float4*>(&lwn[k0 + 1][cg * 4]);
            float4 wn2 = *reinterpret_cast<const float4*>(&lwn[k0 + 2][cg * 4]);
            float4 wn3 = *reinterpret_cast<const float4*>(&lwn[k0 + 3][cg * 4]);
            #pragma unroll
            for (int i = 0; i < 4; ++i) {
                int nl = ns * 4 + i;
                float4 xv = *reinterpret_cast<const float4*>(&lx[nl][kc * 32 + k0]);
                float4 av = *reinterpret_cast<const float4*>(&la[nl][kc * 32 + k0]);
                FMA4(acc[i], xv.x, ws0);
                FMA4(acc[i], xv.y, ws1);
                FMA4(acc[i], xv.z, ws2);
                FMA4(acc[i], xv.w, ws3);
                FMA4(acc[i], av.x, wn0);
                FMA4(acc[i], av.y, wn1);
                FMA4(acc[i], av.z, wn2);
                FMA4(acc[i], av.w, wn3);
            }
        }
    }

    float4 b = *reinterpret_cast<const float4*>(bias + cg * 4);
    #pragma unroll
    for (int i = 0; i < 4; ++i) {
        int n = nb + ns * 4 + i;
        float4 r;
        r.x = acc[i].x + b.x;
        r.y = acc[i].y + b.y;
        r.z = acc[i].z + b.z;
        r.w = acc[i].w + b.w;
        *reinterpret_cast<float4*>(out + n * D + cg * 4) = r;
    }
}

extern "C" void kernel_launch(void* const* d_in, const int* in_sizes, int n_in,
                              void* d_out, int out_size, void* d_ws, size_t ws_size,
                              hipStream_t stream) {
    const float* x     = (const float*)d_in[0];
    const int* ei      = (const int*)d_in[1];     // int inputs arrive as int32
    const float* Ws    = (const float*)d_in[2];
    const float* Wn    = (const float*)d_in[3];
    const float* bias  = (const float*)d_in[4];
    float* out = (float*)d_out;

    const int eb = (N_EDGES + 255) / 256;     // 6250
    const int nbk = (N_NODES + 255) / 256;    // 391

    csr_zero<<<nbk, 256, 0, stream>>>();
    csr_hist<<<eb, 256, 0, stream>>>(ei);
    csr_scanA<<<NB_SCAN, 256, 0, stream>>>();
    csr_scanB<<<1, 64, 0, stream>>>();
    csr_scanC<<<NB_SCAN, 256, 0, stream>>>();
    csr_fill<<<eb, 256, 0, stream>>>(ei);

    sag_gather<<<(N_NODES * 32) / 256, 256, 0, stream>>>(x, out);   // 12500 blocks
    sag_gemm<<<N_NODES / 32, 256, 0, stream>>>(x, Ws, Wn, bias, out); // 3125 blocks
}

// Round 5
// 340.893 us; speedup vs baseline: 8.6152x; 1.3833x over previous
//
#include <hip/hip_runtime.h>

#define N_NODES 100000
#define N_EDGES 1600000
#define D 128

typedef __attribute__((ext_vector_type(8))) short bf16x8;
typedef __attribute__((ext_vector_type(4))) float f32x4;

// ---- scratch in the module's device data segment (no d_ws dependency) ----
#define NB_SCAN 98   // ceil(100000/1024)
__device__ int g_hist[N_NODES];
__device__ int g_rowptr[N_NODES + 1];
__device__ int g_cursor[N_NODES];
__device__ int g_bsum[NB_SCAN];
__device__ int g_boff[NB_SCAN];
__device__ int g_csr[N_EDGES];
__device__ unsigned short g_xh[N_NODES * D];     // x in bf16
__device__ unsigned short g_ah[N_NODES * D];     // a = mean-agg - x, in bf16
__device__ unsigned short g_wh[256 * D];         // [Ws;Wn] transposed [n][k], pre-swizzled

__device__ inline unsigned rne1(float f) {       // f32 -> bf16 bits, round-nearest-even
    unsigned b = __float_as_uint(f);
    return (b + 0x7FFFu + ((b >> 16) & 1u)) >> 16;
}
__device__ inline unsigned pack2(float a, float b) { return rne1(a) | (rne1(b) << 16); }
__device__ inline float bflo(unsigned u) { return __uint_as_float(u << 16); }
__device__ inline float bfhi(unsigned u) { return __uint_as_float(u & 0xFFFF0000u); }

// x (f32, 12.8M) -> g_xh (bf16). 1.6M uint4 chunks, one per thread.
__global__ __launch_bounds__(256) void cvt_x(const float* __restrict__ x)
{
    const int i = blockIdx.x * 256 + threadIdx.x;   // grid = exactly 1.6M threads
    const float4 f0 = reinterpret_cast<const float4*>(x)[i * 2 + 0];
    const float4 f1 = reinterpret_cast<const float4*>(x)[i * 2 + 1];
    uint4 o;
    o.x = pack2(f0.x, f0.y);
    o.y = pack2(f0.z, f0.w);
    o.z = pack2(f1.x, f1.y);
    o.w = pack2(f1.z, f1.w);
    reinterpret_cast<uint4*>(g_xh)[i] = o;
}

// Build g_wh: element (n, k) of B = [Ws; Wn] (K=256 x N=128), stored transposed
// [n][k] with 16B-chunk XOR swizzle (chunk ^= n&7) for conflict-free ds_read_b128.
__global__ __launch_bounds__(256) void cvt_w(const float* __restrict__ Ws,
                                             const float* __restrict__ Wn)
{
    const int tid = blockIdx.x * 256 + threadIdx.x;   // 32768
    const int k = tid >> 7, n = tid & 127;
    const float v = (k < 128) ? Ws[k * 128 + n] : Wn[(k - 128) * 128 + n];
    const int idx = n * 256 + (((k >> 3) ^ (n & 7)) << 3) + (k & 7);
    g_wh[idx] = (unsigned short)rne1(v);
}

__global__ __launch_bounds__(256) void csr_zero()
{
    int i = blockIdx.x * 256 + threadIdx.x;
    if (i < N_NODES) g_hist[i] = 0;
}

__global__ __launch_bounds__(256) void csr_hist(const int* __restrict__ ei)
{
    int e = blockIdx.x * 256 + threadIdx.x;
    if (e < N_EDGES) atomicAdd(&g_hist[ei[N_EDGES + e]], 1);
}

__global__ __launch_bounds__(256) void csr_scanA()
{
    __shared__ int lds[256];
    const int b = blockIdx.x, t = threadIdx.x;
    const int base = b * 1024 + t * 4;
    int v0 = (base + 0 < N_NODES) ? g_hist[base + 0] : 0;
    int v1 = (base + 1 < N_NODES) ? g_hist[base + 1] : 0;
    int v2 = (base + 2 < N_NODES) ? g_hist[base + 2] : 0;
    int v3 = (base + 3 < N_NODES) ? g_hist[base + 3] : 0;
    const int s = v0 + v1 + v2 + v3;
    lds[t] = s;
    __syncthreads();
    for (int off = 1; off < 256; off <<= 1) {
        int add = (t >= off) ? lds[t - off] : 0;
        __syncthreads();
        lds[t] += add;
        __syncthreads();
    }
    int e = lds[t] - s;
    if (base + 0 < N_NODES) g_rowptr[base + 0] = e;           e += v0;
    if (base + 1 < N_NODES) g_rowptr[base + 1] = e;           e += v1;
    if (base + 2 < N_NODES) g_rowptr[base + 2] = e;           e += v2;
    if (base + 3 < N_NODES) g_rowptr[base + 3] = e;
    if (t == 255) g_bsum[b] = lds[255];
}

__global__ __launch_bounds__(64) void csr_scanB()
{
    if (threadIdx.x == 0 && blockIdx.x == 0) {
        int run = 0;
        for (int b = 0; b < NB_SCAN; ++b) { g_boff[b] = run; run += g_bsum[b]; }
        g_rowptr[N_NODES] = run;
    }
}

__global__ __launch_bounds__(256) void csr_scanC()
{
    const int b = blockIdx.x, t = threadIdx.x;
    const int base = b * 1024 + t * 4;
    const int off = g_boff[b];
    #pragma unroll
    for (int k = 0; k < 4; ++k) {
        int i = base + k;
        if (i < N_NODES) {
            int r = g_rowptr[i] + off;
            g_rowptr[i] = r;
            g_cursor[i] = r;
        }
    }
}

__global__ __launch_bounds__(256) void csr_fill(const int* __restrict__ ei)
{
    int e = blockIdx.x * 256 + threadIdx.x;
    if (e < N_EDGES) {
        int dst = ei[N_EDGES + e];
        int pos = atomicAdd(&g_cursor[dst], 1);
        g_csr[pos] = ei[e];
    }
}

// Pull-gather in bf16: g_ah[n] = bf16( (sum xh[src]) / deg - xh[n] ), 0 if deg==0.
// 16 lanes per node, uint4 (8 bf16) per lane; 16 nodes per 256-thread block.
__global__ __launch_bounds__(256) void sag_gather()
{
    const int g = blockIdx.x * 256 + threadIdx.x;   // grid covers exactly 100000*16
    const int node = g >> 4;
    const int lane = g & 15;
    const int beg = g_rowptr[node];
    const int end = g_rowptr[node + 1];
    const int deg = end - beg;
    const uint4* __restrict__ x16 = reinterpret_cast<const uint4*>(g_xh);  // row = 16 chunks

    float acc[8];
    #pragma unroll
    for (int i = 0; i < 8; ++i) acc[i] = 0.f;

    for (int base = beg; base < end; base += 16) {
        const int cnt = min(16, end - base);
        int sid = (lane < cnt) ? g_csr[base + lane] : 0;
        int j = 0;
        for (; j + 4 <= cnt; j += 4) {
            int s0 = __shfl(sid, j + 0, 16);
            int s1 = __shfl(sid, j + 1, 16);
            int s2 = __shfl(sid, j + 2, 16);
            int s3 = __shfl(sid, j + 3, 16);
            uint4 v0 = x16[s0 * 16 + lane];
            uint4 v1 = x16[s1 * 16 + lane];
            uint4 v2 = x16[s2 * 16 + lane];
            uint4 v3 = x16[s3 * 16 + lane];
            acc[0] += bflo(v0.x); acc[1] += bfhi(v0.x); acc[2] += bflo(v0.y); acc[3] += bfhi(v0.y);
            acc[4] += bflo(v0.z); acc[5] += bfhi(v0.z); acc[6] += bflo(v0.w); acc[7] += bfhi(v0.w);
            acc[0] += bflo(v1.x); acc[1] += bfhi(v1.x); acc[2] += bflo(v1.y); acc[3] += bfhi(v1.y);
            acc[4] += bflo(v1.z); acc[5] += bfhi(v1.z); acc[6] += bflo(v1.w); acc[7] += bfhi(v1.w);
            acc[0] += bflo(v2.x); acc[1] += bfhi(v2.x); acc[2] += bflo(v2.y); acc[3] += bfhi(v2.y);
            acc[4] += bflo(v2.z); acc[5] += bfhi(v2.z); acc[6] += bflo(v2.w); acc[7] += bfhi(v2.w);
            acc[0] += bflo(v3.x); acc[1] += bfhi(v3.x); acc[2] += bflo(v3.y); acc[3] += bfhi(v3.y);
            acc[4] += bflo(v3.z); acc[5] += bfhi(v3.z); acc[6] += bflo(v3.w); acc[7] += bfhi(v3.w);
        }
        for (; j < cnt; ++j) {
            int s = __shfl(sid, j, 16);
            uint4 v = x16[s * 16 + lane];
            acc[0] += bflo(v.x); acc[1] += bfhi(v.x); acc[2] += bflo(v.y); acc[3] += bfhi(v.y);
            acc[4] += bflo(v.z); acc[5] += bfhi(v.z); acc[6] += bflo(v.w); acc[7] += bfhi(v.w);
        }
    }

    uint4 res = make_uint4(0u, 0u, 0u, 0u);
    if (deg > 0) {
        const float inv = 1.f / (float)deg;
        const uint4 xv = x16[node * 16 + lane];
        float r0 = acc[0] * inv - bflo(xv.x), r1 = acc[1] * inv - bfhi(xv.x);
        float r2 = acc[2] * inv - bflo(xv.y), r3 = acc[3] * inv - bfhi(xv.y);
        float r4 = acc[4] * inv - bflo(xv.z), r5 = acc[5] * inv - bfhi(xv.z);
        float r6 = acc[6] * inv - bflo(xv.w), r7 = acc[7] * inv - bfhi(xv.w);
        res.x = pack2(r0, r1); res.y = pack2(r2, r3);
        res.z = pack2(r4, r5); res.w = pack2(r6, r7);
    }
    reinterpret_cast<uint4*>(g_ah)[node * 16 + lane] = res;
}

// MFMA GEMM: out = [xh | ah] (N x 256 bf16) @ [Ws;Wn] (256 x 128 bf16) + bias, f32 out.
// 256 threads = 4 waves; wave w owns 32 rows (2 x 16-row A tiles); block = 128 rows.
// B (64KB bf16) staged in LDS, XOR-swizzled (done at cvt_w), ds_read_b128 conflict-free.
__global__ __launch_bounds__(256) void sag_gemm_mfma(
    const float* __restrict__ bias,
    float* __restrict__ out)
{
    __shared__ char lB[65536];

    const int t = threadIdx.x;
    // Stage pre-swizzled g_wh -> LDS with a linear vector copy (16 x 16B per thread).
    {
        const float4* __restrict__ src = reinterpret_cast<const float4*>(g_wh);
        float4* dst = reinterpret_cast<float4*>(lB);
        #pragma unroll
        for (int i = 0; i < 16; ++i) dst[t + i * 256] = src[t + i * 256];
    }
    __syncthreads();

    const int w = t >> 6, l = t & 63;
    const int l15 = l & 15, lg = l >> 4;
    const int rbase = blockIdx.x * 128 + w * 32;

    // A fragments: 2 row tiles x 8 k-steps, each 8 bf16 per lane.
    // A[m = l&15][k = kt*32 + lg*8 + j]; rows clamped (tail block) - stores are guarded.
    const int r0 = min(rbase + l15, N_NODES - 1);
    const int r1 = min(rbase + 16 + l15, N_NODES - 1);
    const bf16x8* __restrict__ xh8 = reinterpret_cast<const bf16x8*>(g_xh);  // row = 16 chunks
    const bf16x8* __restrict__ ah8 = reinterpret_cast<const bf16x8*>(g_ah);
    bf16x8 a0[8], a1[8];
    #pragma unroll
    for (int kt = 0; kt < 4; ++kt) {
        a0[kt]     = xh8[r0 * 16 + kt * 4 + lg];
        a1[kt]     = xh8[r1 * 16 + kt * 4 + lg];
        a0[kt + 4] = ah8[r0 * 16 + kt * 4 + lg];
        a1[kt + 4] = ah8[r1 * 16 + kt * 4 + lg];
    }

    #pragma unroll
    for (int ct = 0; ct < 8; ++ct) {
        const int n = ct * 16 + l15;
        f32x4 acc0 = {0.f, 0.f, 0.f, 0.f};
        f32x4 acc1 = {0.f, 0.f, 0.f, 0.f};
        #pragma unroll
        for (int kt = 0; kt < 8; ++kt) {
            const int kchunk = kt * 4 + lg;
            const bf16x8 b = *reinterpret_cast<const bf16x8*>(
                &lB[n * 512 + ((kchunk ^ (n & 7)) << 4)]);
            acc0 = __builtin_amdgcn_mfma_f32_16x16x32_bf16(a0[kt], b, acc0, 0, 0, 0);
            acc1 = __builtin_amdgcn_mfma_f32_16x16x32_bf16(a1[kt], b, acc1, 0, 0, 0);
        }
        const float bv = bias[n];
        #pragma unroll
        for (int i = 0; i < 4; ++i) {
            const int m0 = rbase + lg * 4 + i;        // D: row = 4*(l>>4)+i, col = l&15
            if (m0 < N_NODES)      out[m0 * D + n] = acc0[i] + bv;
            const int m1 = m0 + 16;
            if (m1 < N_NODES)      out[m1 * D + n] = acc1[i] + bv;
        }
    }
}

extern "C" void kernel_launch(void* const* d_in, const int* in_sizes, int n_in,
                              void* d_out, int out_size, void* d_ws, size_t ws_size,
                              hipStream_t stream) {
    const float* x     = (const float*)d_in[0];
    const int* ei      = (const int*)d_in[1];     // int inputs arrive as int32
    const float* Ws    = (const float*)d_in[2];
    const float* Wn    = (const float*)d_in[3];
    const float* bias  = (const float*)d_in[4];
    float* out = (float*)d_out;

    const int eb  = (N_EDGES + 255) / 256;    // 6250
    const int nbk = (N_NODES + 255) / 256;    // 391

    cvt_x<<<(N_NODES * D / 8) / 256, 256, 0, stream>>>(x);   // 6250 blocks
    cvt_w<<<128, 256, 0, stream>>>(Ws, Wn);

    csr_zero<<<nbk, 256, 0, stream>>>();
    csr_hist<<<eb, 256, 0, stream>>>(ei);
    csr_scanA<<<NB_SCAN, 256, 0, stream>>>();
    csr_scanB<<<1, 64, 0, stream>>>();
    csr_scanC<<<NB_SCAN, 256, 0, stream>>>();
    csr_fill<<<eb, 256, 0, stream>>>(ei);

    sag_gather<<<(N_NODES * 16) / 256, 256, 0, stream>>>();          // 6250 blocks
    sag_gemm_mfma<<<(N_NODES + 127) / 128, 256, 0, stream>>>(bias, out); // 782 blocks
}

// Round 6
// 176.923 us; speedup vs baseline: 16.5997x; 1.9268x over previous
//
#include <hip/hip_runtime.h>

#define N_NODES 100000
#define N_EDGES 1600000
#define D 128

typedef __attribute__((ext_vector_type(8))) short bf16x8;
typedef __attribute__((ext_vector_type(4))) float f32x4;

// ---- bucketing geometry ----
#define BSHIFT 8
#define BNODES 256                       // nodes per bucket
#define NBUCK 391                        // ceil(100000/256)
#define BCAP 8192                        // pairs capacity per bucket (mean 4092, uniform)
#define EPB 4096                         // edges per bin_pass block

// ---- scratch in the module's device data segment ----
__device__ int g_bcur[NBUCK];            // bucket cursors (== counts after bin_pass)
__device__ int g_bbase[NBUCK];           // exclusive scan of counts
__device__ int g_rowptr[N_NODES + 1];
__device__ int g_csr[N_EDGES];
__device__ unsigned long long g_pairs[(size_t)NBUCK * BCAP];
__device__ unsigned short g_xh[N_NODES * D];     // x in bf16
__device__ unsigned short g_ah[N_NODES * D];     // a = mean-agg - x, in bf16
__device__ unsigned short g_wh[256 * D];         // [Ws;Wn] transposed [n][k], pre-swizzled

__device__ inline unsigned rne1(float f) {       // f32 -> bf16 bits, round-nearest-even
    unsigned b = __float_as_uint(f);
    return (b + 0x7FFFu + ((b >> 16) & 1u)) >> 16;
}
__device__ inline unsigned pack2(float a, float b) { return rne1(a) | (rne1(b) << 16); }
__device__ inline float bflo(unsigned u) { return __uint_as_float(u << 16); }
__device__ inline float bfhi(unsigned u) { return __uint_as_float(u & 0xFFFF0000u); }

// x (f32, 12.8M) -> g_xh (bf16). 1.6M uint4 chunks, one per thread.
__global__ __launch_bounds__(256) void cvt_x(const float* __restrict__ x)
{
    const int i = blockIdx.x * 256 + threadIdx.x;
    const float4 f0 = reinterpret_cast<const float4*>(x)[i * 2 + 0];
    const float4 f1 = reinterpret_cast<const float4*>(x)[i * 2 + 1];
    uint4 o;
    o.x = pack2(f0.x, f0.y);
    o.y = pack2(f0.z, f0.w);
    o.z = pack2(f1.x, f1.y);
    o.w = pack2(f1.z, f1.w);
    reinterpret_cast<uint4*>(g_xh)[i] = o;
}

// Build g_wh: element (n, k) of B = [Ws; Wn] (K=256 x N=128), stored transposed
// [n][k] with 16B-chunk XOR swizzle (chunk ^= n&7) for conflict-free ds_read_b128.
__global__ __launch_bounds__(256) void cvt_w(const float* __restrict__ Ws,
                                             const float* __restrict__ Wn)
{
    const int tid = blockIdx.x * 256 + threadIdx.x;   // 32768
    const int k = tid >> 7, n = tid & 127;
    const float v = (k < 128) ? Ws[k * 128 + n] : Wn[(k - 128) * 128 + n];
    const int idx = n * 256 + (((k >> 3) ^ (n & 7)) << 3) + (k & 7);
    g_wh[idx] = (unsigned short)rne1(v);
}

__global__ __launch_bounds__(256) void zero_bcur()
{
    int i = blockIdx.x * 256 + threadIdx.x;
    if (i < NBUCK) g_bcur[i] = 0;
}

// Pass 1: bin edges into per-bucket pair segments (bucket = dst>>8).
// Per block: LDS count -> one global atomic per touched bucket -> LDS-cursor scatter.
__global__ __launch_bounds__(256) void bin_pass(const int* __restrict__ ei)
{
    __shared__ int cnt[NBUCK];
    __shared__ int cur[NBUCK];
    const int t = threadIdx.x;
    const int e0 = blockIdx.x * EPB;

    for (int b = t; b < NBUCK; b += 256) cnt[b] = 0;
    __syncthreads();

    int dstv[16], srcv[16];
    #pragma unroll
    for (int i = 0; i < 16; ++i) {
        const int e = e0 + i * 256 + t;
        if (e < N_EDGES) {
            dstv[i] = ei[N_EDGES + e];
            srcv[i] = ei[e];
            atomicAdd(&cnt[dstv[i] >> BSHIFT], 1);
        } else {
            dstv[i] = -1;
        }
    }
    __syncthreads();

    for (int b = t; b < NBUCK; b += 256) {
        const int c = cnt[b];
        cur[b] = (c > 0) ? atomicAdd(&g_bcur[b], c) : 0;
    }
    __syncthreads();

    #pragma unroll
    for (int i = 0; i < 16; ++i) {
        if (dstv[i] >= 0) {
            const int b = dstv[i] >> BSHIFT;
            const int r = atomicAdd(&cur[b], 1);
            g_pairs[(size_t)b * BCAP + r] =
                ((unsigned long long)(unsigned)dstv[i] << 32) | (unsigned)srcv[i];
        }
    }
}

// Scan 391 bucket counts -> g_bbase (exclusive); write rowptr[N] = total.
__global__ __launch_bounds__(512) void bucket_scan()
{
    __shared__ int s[512];
    __shared__ int c[512];
    const int t = threadIdx.x;
    const int v = (t < NBUCK) ? g_bcur[t] : 0;
    c[t] = v; s[t] = v;
    __syncthreads();
    for (int off = 1; off < 512; off <<= 1) {
        int add = (t >= off) ? s[t - off] : 0;
        __syncthreads();
        s[t] += add;
        __syncthreads();
    }
    if (t < NBUCK) g_bbase[t] = s[t] - c[t];
    if (t == NBUCK - 1) g_rowptr[N_NODES] = s[t];   // == N_EDGES
}

// Pass 2: one block per bucket. Per-node counts -> local scan -> g_rowptr,
// then place src into g_csr via LDS cursors. All csr writes land in the
// bucket's ~16KB span -> L2-resident, single writeback.
__global__ __launch_bounds__(256) void bucket_build()
{
    __shared__ int lcnt[BNODES];
    __shared__ int lsum[BNODES];
    const int t = threadIdx.x;
    const int b = blockIdx.x;
    const int nE = g_bcur[b];
    const int base_edge = g_bbase[b];
    const unsigned long long* __restrict__ seg = &g_pairs[(size_t)b * BCAP];

    lcnt[t] = 0;
    __syncthreads();
    for (int i = t; i < nE; i += 256) {
        const int dst = (int)(seg[i] >> 32);
        atomicAdd(&lcnt[dst & (BNODES - 1)], 1);
    }
    __syncthreads();
    lsum[t] = lcnt[t];
    __syncthreads();
    for (int off = 1; off < 256; off <<= 1) {
        int add = (t >= off) ? lsum[t - off] : 0;
        __syncthreads();
        lsum[t] += add;
        __syncthreads();
    }
    const int excl = lsum[t] - lcnt[t];
    const int node = (b << BSHIFT) + t;
    if (node < N_NODES) g_rowptr[node] = base_edge + excl;
    __syncthreads();
    lsum[t] = base_edge + excl;     // reuse as running cursor
    __syncthreads();
    for (int i = t; i < nE; i += 256) {
        const unsigned long long p = seg[i];
        const int loc = ((int)(p >> 32)) & (BNODES - 1);
        const int pos = atomicAdd(&lsum[loc], 1);
        g_csr[pos] = (int)(p & 0xFFFFFFFFull);
    }
}

// Pull-gather in bf16: g_ah[n] = bf16( (sum xh[src]) / deg - xh[n] ), 0 if deg==0.
// 16 lanes per node, uint4 (8 bf16) per lane; 16 nodes per 256-thread block.
__global__ __launch_bounds__(256) void sag_gather()
{
    const int g = blockIdx.x * 256 + threadIdx.x;
    const int node = g >> 4;
    const int lane = g & 15;
    const int beg = g_rowptr[node];
    const int end = g_rowptr[node + 1];
    const int deg = end - beg;
    const uint4* __restrict__ x16 = reinterpret_cast<const uint4*>(g_xh);

    float acc[8];
    #pragma unroll
    for (int i = 0; i < 8; ++i) acc[i] = 0.f;

    for (int base = beg; base < end; base += 16) {
        const int cnt = min(16, end - base);
        int sid = (lane < cnt) ? g_csr[base + lane] : 0;
        int j = 0;
        for (; j + 4 <= cnt; j += 4) {
            int s0 = __shfl(sid, j + 0, 16);
            int s1 = __shfl(sid, j + 1, 16);
            int s2 = __shfl(sid, j + 2, 16);
            int s3 = __shfl(sid, j + 3, 16);
            uint4 v0 = x16[s0 * 16 + lane];
            uint4 v1 = x16[s1 * 16 + lane];
            uint4 v2 = x16[s2 * 16 + lane];
            uint4 v3 = x16[s3 * 16 + lane];
            acc[0] += bflo(v0.x); acc[1] += bfhi(v0.x); acc[2] += bflo(v0.y); acc[3] += bfhi(v0.y);
            acc[4] += bflo(v0.z); acc[5] += bfhi(v0.z); acc[6] += bflo(v0.w); acc[7] += bfhi(v0.w);
            acc[0] += bflo(v1.x); acc[1] += bfhi(v1.x); acc[2] += bflo(v1.y); acc[3] += bfhi(v1.y);
            acc[4] += bflo(v1.z); acc[5] += bfhi(v1.z); acc[6] += bflo(v1.w); acc[7] += bfhi(v1.w);
            acc[0] += bflo(v2.x); acc[1] += bfhi(v2.x); acc[2] += bflo(v2.y); acc[3] += bfhi(v2.y);
            acc[4] += bflo(v2.z); acc[5] += bfhi(v2.z); acc[6] += bflo(v2.w); acc[7] += bfhi(v2.w);
            acc[0] += bflo(v3.x); acc[1] += bfhi(v3.x); acc[2] += bflo(v3.y); acc[3] += bfhi(v3.y);
            acc[4] += bflo(v3.z); acc[5] += bfhi(v3.z); acc[6] += bflo(v3.w); acc[7] += bfhi(v3.w);
        }
        for (; j < cnt; ++j) {
            int s = __shfl(sid, j, 16);
            uint4 v = x16[s * 16 + lane];
            acc[0] += bflo(v.x); acc[1] += bfhi(v.x); acc[2] += bflo(v.y); acc[3] += bfhi(v.y);
            acc[4] += bflo(v.z); acc[5] += bfhi(v.z); acc[6] += bflo(v.w); acc[7] += bfhi(v.w);
        }
    }

    uint4 res = make_uint4(0u, 0u, 0u, 0u);
    if (deg > 0) {
        const float inv = 1.f / (float)deg;
        const uint4 xv = x16[node * 16 + lane];
        float r0 = acc[0] * inv - bflo(xv.x), r1 = acc[1] * inv - bfhi(xv.x);
        float r2 = acc[2] * inv - bflo(xv.y), r3 = acc[3] * inv - bfhi(xv.y);
        float r4 = acc[4] * inv - bflo(xv.z), r5 = acc[5] * inv - bfhi(xv.z);
        float r6 = acc[6] * inv - bflo(xv.w), r7 = acc[7] * inv - bfhi(xv.w);
        res.x = pack2(r0, r1); res.y = pack2(r2, r3);
        res.z = pack2(r4, r5); res.w = pack2(r6, r7);
    }
    reinterpret_cast<uint4*>(g_ah)[node * 16 + lane] = res;
}

// MFMA GEMM: out = [xh | ah] (N x 256 bf16) @ [Ws;Wn] (256 x 128 bf16) + bias, f32 out.
__global__ __launch_bounds__(256) void sag_gemm_mfma(
    const float* __restrict__ bias,
    float* __restrict__ out)
{
    __shared__ char lB[65536];

    const int t = threadIdx.x;
    {
        const float4* __restrict__ src = reinterpret_cast<const float4*>(g_wh);
        float4* dst = reinterpret_cast<float4*>(lB);
        #pragma unroll
        for (int i = 0; i < 16; ++i) dst[t + i * 256] = src[t + i * 256];
    }
    __syncthreads();

    const int w = t >> 6, l = t & 63;
    const int l15 = l & 15, lg = l >> 4;
    const int rbase = blockIdx.x * 128 + w * 32;

    const int r0 = min(rbase + l15, N_NODES - 1);
    const int r1 = min(rbase + 16 + l15, N_NODES - 1);
    const bf16x8* __restrict__ xh8 = reinterpret_cast<const bf16x8*>(g_xh);
    const bf16x8* __restrict__ ah8 = reinterpret_cast<const bf16x8*>(g_ah);
    bf16x8 a0[8], a1[8];
    #pragma unroll
    for (int kt = 0; kt < 4; ++kt) {
        a0[kt]     = xh8[r0 * 16 + kt * 4 + lg];
        a1[kt]     = xh8[r1 * 16 + kt * 4 + lg];
        a0[kt + 4] = ah8[r0 * 16 + kt * 4 + lg];
        a1[kt + 4] = ah8[r1 * 16 + kt * 4 + lg];
    }

    #pragma unroll
    for (int ct = 0; ct < 8; ++ct) {
        const int n = ct * 16 + l15;
        f32x4 acc0 = {0.f, 0.f, 0.f, 0.f};
        f32x4 acc1 = {0.f, 0.f, 0.f, 0.f};
        #pragma unroll
        for (int kt = 0; kt < 8; ++kt) {
            const int kchunk = kt * 4 + lg;
            const bf16x8 b = *reinterpret_cast<const bf16x8*>(
                &lB[n * 512 + ((kchunk ^ (n & 7)) << 4)]);
            acc0 = __builtin_amdgcn_mfma_f32_16x16x32_bf16(a0[kt], b, acc0, 0, 0, 0);
            acc1 = __builtin_amdgcn_mfma_f32_16x16x32_bf16(a1[kt], b, acc1, 0, 0, 0);
        }
        const float bv = bias[n];
        #pragma unroll
        for (int i = 0; i < 4; ++i) {
            const int m0 = rbase + lg * 4 + i;
            if (m0 < N_NODES)      out[m0 * D + n] = acc0[i] + bv;
            const int m1 = m0 + 16;
            if (m1 < N_NODES)      out[m1 * D + n] = acc1[i] + bv;
        }
    }
}

extern "C" void kernel_launch(void* const* d_in, const int* in_sizes, int n_in,
                              void* d_out, int out_size, void* d_ws, size_t ws_size,
                              hipStream_t stream) {
    const float* x     = (const float*)d_in[0];
    const int* ei      = (const int*)d_in[1];
    const float* Ws    = (const float*)d_in[2];
    const float* Wn    = (const float*)d_in[3];
    const float* bias  = (const float*)d_in[4];
    float* out = (float*)d_out;

    cvt_x<<<(N_NODES * D / 8) / 256, 256, 0, stream>>>(x);   // 6250 blocks
    cvt_w<<<128, 256, 0, stream>>>(Ws, Wn);

    zero_bcur<<<2, 256, 0, stream>>>();
    bin_pass<<<(N_EDGES + EPB - 1) / EPB, 256, 0, stream>>>(ei);  // 391 blocks
    bucket_scan<<<1, 512, 0, stream>>>();
    bucket_build<<<NBUCK, 256, 0, stream>>>();                    // 391 blocks

    sag_gather<<<(N_NODES * 16) / 256, 256, 0, stream>>>();           // 6250 blocks
    sag_gemm_mfma<<<(N_NODES + 127) / 128, 256, 0, stream>>>(bias, out); // 782 blocks
}

// Round 7
// 172.879 us; speedup vs baseline: 16.9880x; 1.0234x over previous
//
#include <hip/hip_runtime.h>

#define N_NODES 100000
#define N_EDGES 1600000
#define D 128

typedef __attribute__((ext_vector_type(8))) short bf16x8;
typedef __attribute__((ext_vector_type(4))) float f32x4;

// ---- bucketing geometry ----
#define BSHIFT 8
#define BNODES 256                       // nodes per bucket
#define NBUCK 391                        // ceil(100000/256)
#define BCAP 8192                        // pairs capacity per bucket (mean 4092)
#define EPB 4096                         // edges per bin_pass block

// ---- scratch in the module's device data segment ----
__device__ int g_bcur[NBUCK];            // bucket cursors (== counts after bin_pass)
__device__ int g_rowptr[N_NODES + 1];
__device__ int g_csr[N_EDGES];
__device__ unsigned g_pairs[(size_t)NBUCK * BCAP];   // (loc<<24)|src
__device__ unsigned short g_xh[N_NODES * D];     // x in bf16
__device__ unsigned short g_ah[N_NODES * D];     // a = mean-agg - x, in bf16
__device__ unsigned short g_wh[256 * D];         // [Ws;Wn] transposed [n][k], pre-swizzled

__device__ inline unsigned rne1(float f) {       // f32 -> bf16 bits, round-nearest-even
    unsigned b = __float_as_uint(f);
    return (b + 0x7FFFu + ((b >> 16) & 1u)) >> 16;
}
__device__ inline unsigned pack2(float a, float b) { return rne1(a) | (rne1(b) << 16); }
__device__ inline float bflo(unsigned u) { return __uint_as_float(u << 16); }
__device__ inline float bfhi(unsigned u) { return __uint_as_float(u & 0xFFFF0000u); }

// x (f32, 12.8M) -> g_xh (bf16). 1.6M uint4 chunks, one per thread.
__global__ __launch_bounds__(256) void cvt_x(const float* __restrict__ x)
{
    const int i = blockIdx.x * 256 + threadIdx.x;
    const float4 f0 = reinterpret_cast<const float4*>(x)[i * 2 + 0];
    const float4 f1 = reinterpret_cast<const float4*>(x)[i * 2 + 1];
    uint4 o;
    o.x = pack2(f0.x, f0.y);
    o.y = pack2(f0.z, f0.w);
    o.z = pack2(f1.x, f1.y);
    o.w = pack2(f1.z, f1.w);
    reinterpret_cast<uint4*>(g_xh)[i] = o;
}

// Build g_wh (transposed [n][k], 16B-chunk XOR swizzle). Also zeroes bucket
// cursors and writes the constant rowptr terminator (saves two tiny kernels).
__global__ __launch_bounds__(256) void cvt_w(const float* __restrict__ Ws,
                                             const float* __restrict__ Wn)
{
    const int tid = blockIdx.x * 256 + threadIdx.x;   // 32768
    const int k = tid >> 7, n = tid & 127;
    const float v = (k < 128) ? Ws[k * 128 + n] : Wn[(k - 128) * 128 + n];
    const int idx = n * 256 + (((k >> 3) ^ (n & 7)) << 3) + (k & 7);
    g_wh[idx] = (unsigned short)rne1(v);
    if (tid < NBUCK) g_bcur[tid] = 0;
    if (tid == 0) g_rowptr[N_NODES] = N_EDGES;
}

// Pass 1: bin edges into per-bucket segments (bucket = dst>>8).
// Per block: LDS count -> one global atomic per touched bucket -> LDS-cursor scatter.
__global__ __launch_bounds__(256) void bin_pass(const int* __restrict__ ei)
{
    __shared__ int cnt[NBUCK];
    __shared__ int cur[NBUCK];
    const int t = threadIdx.x;
    const int e0 = blockIdx.x * EPB;

    for (int b = t; b < NBUCK; b += 256) cnt[b] = 0;
    __syncthreads();

    int dstv[16], srcv[16];
    #pragma unroll
    for (int i = 0; i < 16; ++i) {
        const int e = e0 + i * 256 + t;
        if (e < N_EDGES) {
            dstv[i] = ei[N_EDGES + e];
            srcv[i] = ei[e];
            atomicAdd(&cnt[dstv[i] >> BSHIFT], 1);
        } else {
            dstv[i] = -1;
        }
    }
    __syncthreads();

    for (int b = t; b < NBUCK; b += 256) {
        const int c = cnt[b];
        cur[b] = (c > 0) ? atomicAdd(&g_bcur[b], c) : 0;
    }
    __syncthreads();

    #pragma unroll
    for (int i = 0; i < 16; ++i) {
        if (dstv[i] >= 0) {
            const int b = dstv[i] >> BSHIFT;
            const int r = atomicAdd(&cur[b], 1);
            g_pairs[(size_t)b * BCAP + r] =
                ((unsigned)(dstv[i] & (BNODES - 1)) << 24) | (unsigned)srcv[i];
        }
    }
}

// Pass 2: one block per bucket. Computes its own edge base (strided reduce of
// lower bucket counts), per-node counts -> local scan -> g_rowptr, then places
// src into g_csr via LDS cursors (writes confined to the bucket's span).
__global__ __launch_bounds__(256) void bucket_build()
{
    __shared__ int red[256];
    __shared__ int lcnt[BNODES];
    __shared__ int lsum[BNODES];
    const int t = threadIdx.x;
    const int b = blockIdx.x;
    const int nE = g_bcur[b];
    const unsigned* __restrict__ seg = &g_pairs[(size_t)b * BCAP];

    // base_edge = sum of counts of buckets < b
    int partial = 0;
    for (int i = t; i < b; i += 256) partial += g_bcur[i];
    red[t] = partial;
    lcnt[t] = 0;
    __syncthreads();
    for (int off = 128; off > 0; off >>= 1) {
        if (t < off) red[t] += red[t + off];
        __syncthreads();
    }
    const int base_edge = red[0];

    for (int i = t; i < nE; i += 256)
        atomicAdd(&lcnt[seg[i] >> 24], 1);
    __syncthreads();
    lsum[t] = lcnt[t];
    __syncthreads();
    for (int off = 1; off < 256; off <<= 1) {
        int add = (t >= off) ? lsum[t - off] : 0;
        __syncthreads();
        lsum[t] += add;
        __syncthreads();
    }
    const int excl = lsum[t] - lcnt[t];
    const int node = (b << BSHIFT) + t;
    if (node < N_NODES) g_rowptr[node] = base_edge + excl;
    __syncthreads();
    lsum[t] = base_edge + excl;     // reuse as running cursor
    __syncthreads();
    for (int i = t; i < nE; i += 256) {
        const unsigned p = seg[i];
        const int pos = atomicAdd(&lsum[p >> 24], 1);
        g_csr[pos] = (int)(p & 0xFFFFFFu);
    }
}

// Pull-gather: one NODE per 64-lane wave. Quarter q = lane>>4 handles rows
// base+4i+q (csr read direct, no shfl dependency); chunk c = lane&15 (16B).
// 16 independent row loads in flight per wave; cross-quarter shfl_xor reduce.
__global__ __launch_bounds__(256) void sag_gather()
{
    const int gt = blockIdx.x * 256 + threadIdx.x;
    const int node = gt >> 6;                 // 25000 blocks -> exactly 100000 waves
    const int q = (gt >> 4) & 3;
    const int c = gt & 15;
    const int beg = g_rowptr[node];
    const int end = g_rowptr[node + 1];
    const int deg = end - beg;
    const uint4* __restrict__ x16 = reinterpret_cast<const uint4*>(g_xh);

    float acc[8];
    #pragma unroll
    for (int i = 0; i < 8; ++i) acc[i] = 0.f;

    int base = beg;
    for (; base + 16 <= end; base += 16) {
        const int s0 = g_csr[base + 0 + q];
        const int s1 = g_csr[base + 4 + q];
        const int s2 = g_csr[base + 8 + q];
        const int s3 = g_csr[base + 12 + q];
        const uint4 v0 = x16[s0 * 16 + c];
        const uint4 v1 = x16[s1 * 16 + c];
        const uint4 v2 = x16[s2 * 16 + c];
        const uint4 v3 = x16[s3 * 16 + c];
        acc[0] += bflo(v0.x); acc[1] += bfhi(v0.x); acc[2] += bflo(v0.y); acc[3] += bfhi(v0.y);
        acc[4] += bflo(v0.z); acc[5] += bfhi(v0.z); acc[6] += bflo(v0.w); acc[7] += bfhi(v0.w);
        acc[0] += bflo(v1.x); acc[1] += bfhi(v1.x); acc[2] += bflo(v1.y); acc[3] += bfhi(v1.y);
        acc[4] += bflo(v1.z); acc[5] += bfhi(v1.z); acc[6] += bflo(v1.w); acc[7] += bfhi(v1.w);
        acc[0] += bflo(v2.x); acc[1] += bfhi(v2.x); acc[2] += bflo(v2.y); acc[3] += bfhi(v2.y);
        acc[4] += bflo(v2.z); acc[5] += bfhi(v2.z); acc[6] += bflo(v2.w); acc[7] += bfhi(v2.w);
        acc[0] += bflo(v3.x); acc[1] += bfhi(v3.x); acc[2] += bflo(v3.y); acc[3] += bfhi(v3.y);
        acc[4] += bflo(v3.z); acc[5] += bfhi(v3.z); acc[6] += bflo(v3.w); acc[7] += bfhi(v3.w);
    }
    for (; base < end; base += 4) {
        if (base + q < end) {
            const int s = g_csr[base + q];
            const uint4 v = x16[s * 16 + c];
            acc[0] += bflo(v.x); acc[1] += bfhi(v.x); acc[2] += bflo(v.y); acc[3] += bfhi(v.y);
            acc[4] += bflo(v.z); acc[5] += bfhi(v.z); acc[6] += bflo(v.w); acc[7] += bfhi(v.w);
        }
    }

    // Reduce across the 4 quarters (lanes q differ by bits 4,5 of lane id).
    #pragma unroll
    for (int i = 0; i < 8; ++i) {
        acc[i] += __shfl_xor(acc[i], 16, 64);
        acc[i] += __shfl_xor(acc[i], 32, 64);
    }

    if (q == 0) {
        uint4 res = make_uint4(0u, 0u, 0u, 0u);
        if (deg > 0) {
            const float inv = 1.f / (float)deg;
            const uint4 xv = x16[node * 16 + c];
            float r0 = acc[0] * inv - bflo(xv.x), r1 = acc[1] * inv - bfhi(xv.x);
            float r2 = acc[2] * inv - bflo(xv.y), r3 = acc[3] * inv - bfhi(xv.y);
            float r4 = acc[4] * inv - bflo(xv.z), r5 = acc[5] * inv - bfhi(xv.z);
            float r6 = acc[6] * inv - bflo(xv.w), r7 = acc[7] * inv - bfhi(xv.w);
            res.x = pack2(r0, r1); res.y = pack2(r2, r3);
            res.z = pack2(r4, r5); res.w = pack2(r6, r7);
        }
        reinterpret_cast<uint4*>(g_ah)[node * 16 + c] = res;
    }
}

// MFMA GEMM: out = [xh | ah] (N x 256 bf16) @ [Ws;Wn] (256 x 128 bf16) + bias, f32 out.
__global__ __launch_bounds__(256) void sag_gemm_mfma(
    const float* __restrict__ bias,
    float* __restrict__ out)
{
    __shared__ char lB[65536];

    const int t = threadIdx.x;
    {
        const float4* __restrict__ src = reinterpret_cast<const float4*>(g_wh);
        float4* dst = reinterpret_cast<float4*>(lB);
        #pragma unroll
        for (int i = 0; i < 16; ++i) dst[t + i * 256] = src[t + i * 256];
    }
    __syncthreads();

    const int w = t >> 6, l = t & 63;
    const int l15 = l & 15, lg = l >> 4;
    const int rbase = blockIdx.x * 128 + w * 32;

    const int r0 = min(rbase + l15, N_NODES - 1);
    const int r1 = min(rbase + 16 + l15, N_NODES - 1);
    const bf16x8* __restrict__ xh8 = reinterpret_cast<const bf16x8*>(g_xh);
    const bf16x8* __restrict__ ah8 = reinterpret_cast<const bf16x8*>(g_ah);
    bf16x8 a0[8], a1[8];
    #pragma unroll
    for (int kt = 0; kt < 4; ++kt) {
        a0[kt]     = xh8[r0 * 16 + kt * 4 + lg];
        a1[kt]     = xh8[r1 * 16 + kt * 4 + lg];
        a0[kt + 4] = ah8[r0 * 16 + kt * 4 + lg];
        a1[kt + 4] = ah8[r1 * 16 + kt * 4 + lg];
    }

    #pragma unroll
    for (int ct = 0; ct < 8; ++ct) {
        const int n = ct * 16 + l15;
        f32x4 acc0 = {0.f, 0.f, 0.f, 0.f};
        f32x4 acc1 = {0.f, 0.f, 0.f, 0.f};
        #pragma unroll
        for (int kt = 0; kt < 8; ++kt) {
            const int kchunk = kt * 4 + lg;
            const bf16x8 b = *reinterpret_cast<const bf16x8*>(
                &lB[n * 512 + ((kchunk ^ (n & 7)) << 4)]);
            acc0 = __builtin_amdgcn_mfma_f32_16x16x32_bf16(a0[kt], b, acc0, 0, 0, 0);
            acc1 = __builtin_amdgcn_mfma_f32_16x16x32_bf16(a1[kt], b, acc1, 0, 0, 0);
        }
        const float bv = bias[n];
        #pragma unroll
        for (int i = 0; i < 4; ++i) {
            const int m0 = rbase + lg * 4 + i;
            if (m0 < N_NODES)      out[m0 * D + n] = acc0[i] + bv;
            const int m1 = m0 + 16;
            if (m1 < N_NODES)      out[m1 * D + n] = acc1[i] + bv;
        }
    }
}

extern "C" void kernel_launch(void* const* d_in, const int* in_sizes, int n_in,
                              void* d_out, int out_size, void* d_ws, size_t ws_size,
                              hipStream_t stream) {
    const float* x     = (const float*)d_in[0];
    const int* ei      = (const int*)d_in[1];
    const float* Ws    = (const float*)d_in[2];
    const float* Wn    = (const float*)d_in[3];
    const float* bias  = (const float*)d_in[4];
    float* out = (float*)d_out;

    cvt_x<<<(N_NODES * D / 8) / 256, 256, 0, stream>>>(x);   // 6250 blocks
    cvt_w<<<128, 256, 0, stream>>>(Ws, Wn);

    bin_pass<<<(N_EDGES + EPB - 1) / EPB, 256, 0, stream>>>(ei);  // 391 blocks
    bucket_build<<<NBUCK, 256, 0, stream>>>();                    // 391 blocks

    sag_gather<<<(N_NODES * 64) / 256, 256, 0, stream>>>();           // 25000 blocks
    sag_gemm_mfma<<<(N_NODES + 127) / 128, 256, 0, stream>>>(bias, out); // 782 blocks
}

// Round 8
// 151.225 us; speedup vs baseline: 19.4205x; 1.1432x over previous
//
#include <hip/hip_runtime.h>

#define N_NODES 100000
#define N_EDGES 1600000
#define D 128

typedef __attribute__((ext_vector_type(8))) short bf16x8;
typedef __attribute__((ext_vector_type(4))) float f32x4;
typedef __attribute__((ext_vector_type(2))) float f32x2;

// ---- bucketing geometry ----
#define BSHIFT 8
#define BNODES 256                       // nodes per bucket
#define NBUCK 391                        // ceil(100000/256)
#define BCAP 8192                        // pairs capacity per bucket (mean 4092)
#define EPB 4096                         // edges per bin_pass block

// ---- scratch in the module's device data segment ----
__device__ int g_bcur[NBUCK];            // bucket cursors (== counts after bin_pass)
__device__ int g_rowptr[N_NODES + 1];
__device__ int g_csr[N_EDGES];
__device__ unsigned g_pairs[(size_t)NBUCK * BCAP];   // (loc<<24)|src
__device__ unsigned short g_xh[N_NODES * D];  // x in bf16 (GEMM A + x[dst])
__device__ uint2 g_xq[N_NODES * 16];          // x in fp8 e4m3 (gather stream), row = 128B
__device__ unsigned short g_ah[N_NODES * D];  // a = mean-agg - x, in bf16
__device__ unsigned short g_wh[256 * D];      // [Ws;Wn] transposed [n][k], pre-swizzled

__device__ inline unsigned rne1(float f) {       // f32 -> bf16 bits, round-nearest-even
    unsigned b = __float_as_uint(f);
    return (b + 0x7FFFu + ((b >> 16) & 1u)) >> 16;
}
__device__ inline unsigned pack2(float a, float b) { return rne1(a) | (rne1(b) << 16); }
__device__ inline float bflo(unsigned u) { return __uint_as_float(u << 16); }
__device__ inline float bfhi(unsigned u) { return __uint_as_float(u & 0xFFFF0000u); }

// Fused prep:
//  blocks [0,6250):    x -> g_xh (bf16) and g_xq (fp8)
//  blocks [6250,6378): build g_wh (transposed, 16B-chunk XOR swizzle)
//  block  6378:        zero bucket cursors, write rowptr terminator
__global__ __launch_bounds__(256) void prep(const float* __restrict__ x,
                                            const float* __restrict__ Ws,
                                            const float* __restrict__ Wn)
{
    const int b = blockIdx.x;
    if (b < 6250) {
        const int i = b * 256 + threadIdx.x;       // uint4 chunk index (1.6M)
        const float4 f0 = reinterpret_cast<const float4*>(x)[i * 2 + 0];
        const float4 f1 = reinterpret_cast<const float4*>(x)[i * 2 + 1];
        uint4 o;
        o.x = pack2(f0.x, f0.y);
        o.y = pack2(f0.z, f0.w);
        o.z = pack2(f1.x, f1.y);
        o.w = pack2(f1.z, f1.w);
        reinterpret_cast<uint4*>(g_xh)[i] = o;
        int lo = __builtin_amdgcn_cvt_pk_fp8_f32(f0.x, f0.y, 0, false);
        lo = __builtin_amdgcn_cvt_pk_fp8_f32(f0.z, f0.w, lo, true);
        int hi = __builtin_amdgcn_cvt_pk_fp8_f32(f1.x, f1.y, 0, false);
        hi = __builtin_amdgcn_cvt_pk_fp8_f32(f1.z, f1.w, hi, true);
        g_xq[i] = make_uint2((unsigned)lo, (unsigned)hi);
    } else if (b < 6378) {
        const int tid = (b - 6250) * 256 + threadIdx.x;   // 32768
        const int k = tid >> 7, n = tid & 127;
        const float v = (k < 128) ? Ws[k * 128 + n] : Wn[(k - 128) * 128 + n];
        const int idx = n * 256 + (((k >> 3) ^ (n & 7)) << 3) + (k & 7);
        g_wh[idx] = (unsigned short)rne1(v);
    } else {
        for (int i = threadIdx.x; i < NBUCK; i += 256) g_bcur[i] = 0;
        if (threadIdx.x == 0) g_rowptr[N_NODES] = N_EDGES;
    }
}

// Pass 1: bin edges into per-bucket segments (bucket = dst>>8).
__global__ __launch_bounds__(256) void bin_pass(const int* __restrict__ ei)
{
    __shared__ int cnt[NBUCK];
    __shared__ int cur[NBUCK];
    const int t = threadIdx.x;
    const int e0 = blockIdx.x * EPB;

    for (int b = t; b < NBUCK; b += 256) cnt[b] = 0;
    __syncthreads();

    int dstv[16], srcv[16];
    #pragma unroll
    for (int i = 0; i < 16; ++i) {
        const int e = e0 + i * 256 + t;
        if (e < N_EDGES) {
            dstv[i] = ei[N_EDGES + e];
            srcv[i] = ei[e];
            atomicAdd(&cnt[dstv[i] >> BSHIFT], 1);
        } else {
            dstv[i] = -1;
        }
    }
    __syncthreads();

    for (int b = t; b < NBUCK; b += 256) {
        const int c = cnt[b];
        cur[b] = (c > 0) ? atomicAdd(&g_bcur[b], c) : 0;
    }
    __syncthreads();

    #pragma unroll
    for (int i = 0; i < 16; ++i) {
        if (dstv[i] >= 0) {
            const int b = dstv[i] >> BSHIFT;
            const int r = atomicAdd(&cur[b], 1);
            g_pairs[(size_t)b * BCAP + r] =
                ((unsigned)(dstv[i] & (BNODES - 1)) << 24) | (unsigned)srcv[i];
        }
    }
}

// Pass 2: one block per bucket -> g_rowptr + g_csr (writes L2-confined).
__global__ __launch_bounds__(256) void bucket_build()
{
    __shared__ int red[256];
    __shared__ int lcnt[BNODES];
    __shared__ int lsum[BNODES];
    const int t = threadIdx.x;
    const int b = blockIdx.x;
    const int nE = g_bcur[b];
    const unsigned* __restrict__ seg = &g_pairs[(size_t)b * BCAP];

    int partial = 0;
    for (int i = t; i < b; i += 256) partial += g_bcur[i];
    red[t] = partial;
    lcnt[t] = 0;
    __syncthreads();
    for (int off = 128; off > 0; off >>= 1) {
        if (t < off) red[t] += red[t + off];
        __syncthreads();
    }
    const int base_edge = red[0];

    for (int i = t; i < nE; i += 256)
        atomicAdd(&lcnt[seg[i] >> 24], 1);
    __syncthreads();
    lsum[t] = lcnt[t];
    __syncthreads();
    for (int off = 1; off < 256; off <<= 1) {
        int add = (t >= off) ? lsum[t - off] : 0;
        __syncthreads();
        lsum[t] += add;
        __syncthreads();
    }
    const int excl = lsum[t] - lcnt[t];
    const int node = (b << BSHIFT) + t;
    if (node < N_NODES) g_rowptr[node] = base_edge + excl;
    __syncthreads();
    lsum[t] = base_edge + excl;     // reuse as running cursor
    __syncthreads();
    for (int i = t; i < nE; i += 256) {
        const unsigned p = seg[i];
        const int pos = atomicAdd(&lsum[p >> 24], 1);
        g_csr[pos] = (int)(p & 0xFFFFFFu);
    }
}

// Pull-gather (fp8 stream): one NODE per 64-lane wave. Quarter q = lane>>4
// handles rows base+4i+q; chunk c = lane&15 (8B = 8 fp8 = elems c*8..c*8+7).
// HW fp8->f32 decode; cross-quarter shfl_xor reduce; a written as bf16.
__global__ __launch_bounds__(256) void sag_gather()
{
    const int gt = blockIdx.x * 256 + threadIdx.x;
    const int node = gt >> 6;
    const int q = (gt >> 4) & 3;
    const int c = gt & 15;
    const int beg = g_rowptr[node];
    const int end = g_rowptr[node + 1];
    const int deg = end - beg;

    float acc[8];
    #pragma unroll
    for (int i = 0; i < 8; ++i) acc[i] = 0.f;

    #define ACC8(v) do {                                                  \
        f32x2 p0 = __builtin_amdgcn_cvt_pk_f32_fp8((v).x, false);         \
        f32x2 p1 = __builtin_amdgcn_cvt_pk_f32_fp8((v).x, true);          \
        f32x2 p2 = __builtin_amdgcn_cvt_pk_f32_fp8((v).y, false);         \
        f32x2 p3 = __builtin_amdgcn_cvt_pk_f32_fp8((v).y, true);          \
        acc[0] += p0.x; acc[1] += p0.y; acc[2] += p1.x; acc[3] += p1.y;   \
        acc[4] += p2.x; acc[5] += p2.y; acc[6] += p3.x; acc[7] += p3.y;   \
    } while (0)

    int base = beg;
    for (; base + 16 <= end; base += 16) {
        const int s0 = g_csr[base + 0 + q];
        const int s1 = g_csr[base + 4 + q];
        const int s2 = g_csr[base + 8 + q];
        const int s3 = g_csr[base + 12 + q];
        const uint2 v0 = g_xq[s0 * 16 + c];
        const uint2 v1 = g_xq[s1 * 16 + c];
        const uint2 v2 = g_xq[s2 * 16 + c];
        const uint2 v3 = g_xq[s3 * 16 + c];
        ACC8(v0); ACC8(v1); ACC8(v2); ACC8(v3);
    }
    for (; base < end; base += 4) {
        if (base + q < end) {
            const int s = g_csr[base + q];
            const uint2 v = g_xq[s * 16 + c];
            ACC8(v);
        }
    }
    #undef ACC8

    #pragma unroll
    for (int i = 0; i < 8; ++i) {
        acc[i] += __shfl_xor(acc[i], 16, 64);
        acc[i] += __shfl_xor(acc[i], 32, 64);
    }

    if (q == 0) {
        uint4 res = make_uint4(0u, 0u, 0u, 0u);
        if (deg > 0) {
            const float inv = 1.f / (float)deg;
            const uint4 xv = reinterpret_cast<const uint4*>(g_xh)[node * 16 + c];
            float r0 = acc[0] * inv - bflo(xv.x), r1 = acc[1] * inv - bfhi(xv.x);
            float r2 = acc[2] * inv - bflo(xv.y), r3 = acc[3] * inv - bfhi(xv.y);
            float r4 = acc[4] * inv - bflo(xv.z), r5 = acc[5] * inv - bfhi(xv.z);
            float r6 = acc[6] * inv - bflo(xv.w), r7 = acc[7] * inv - bfhi(xv.w);
            res.x = pack2(r0, r1); res.y = pack2(r2, r3);
            res.z = pack2(r4, r5); res.w = pack2(r6, r7);
        }
        reinterpret_cast<uint4*>(g_ah)[node * 16 + c] = res;
    }
}

// MFMA GEMM: out = [xh | ah] (N x 256 bf16) @ [Ws;Wn] (256 x 128 bf16) + bias, f32 out.
__global__ __launch_bounds__(256) void sag_gemm_mfma(
    const float* __restrict__ bias,
    float* __restrict__ out)
{
    __shared__ char lB[65536];

    const int t = threadIdx.x;
    {
        const float4* __restrict__ src = reinterpret_cast<const float4*>(g_wh);
        float4* dst = reinterpret_cast<float4*>(lB);
        #pragma unroll
        for (int i = 0; i < 16; ++i) dst[t + i * 256] = src[t + i * 256];
    }
    __syncthreads();

    const int w = t >> 6, l = t & 63;
    const int l15 = l & 15, lg = l >> 4;
    const int rbase = blockIdx.x * 128 + w * 32;

    const int r0 = min(rbase + l15, N_NODES - 1);
    const int r1 = min(rbase + 16 + l15, N_NODES - 1);
    const bf16x8* __restrict__ xh8 = reinterpret_cast<const bf16x8*>(g_xh);
    const bf16x8* __restrict__ ah8 = reinterpret_cast<const bf16x8*>(g_ah);
    bf16x8 a0[8], a1[8];
    #pragma unroll
    for (int kt = 0; kt < 4; ++kt) {
        a0[kt]     = xh8[r0 * 16 + kt * 4 + lg];
        a1[kt]     = xh8[r1 * 16 + kt * 4 + lg];
        a0[kt + 4] = ah8[r0 * 16 + kt * 4 + lg];
        a1[kt + 4] = ah8[r1 * 16 + kt * 4 + lg];
    }

    #pragma unroll
    for (int ct = 0; ct < 8; ++ct) {
        const int n = ct * 16 + l15;
        f32x4 acc0 = {0.f, 0.f, 0.f, 0.f};
        f32x4 acc1 = {0.f, 0.f, 0.f, 0.f};
        #pragma unroll
        for (int kt = 0; kt < 8; ++kt) {
            const int kchunk = kt * 4 + lg;
            const bf16x8 b = *reinterpret_cast<const bf16x8*>(
                &lB[n * 512 + ((kchunk ^ (n & 7)) << 4)]);
            acc0 = __builtin_amdgcn_mfma_f32_16x16x32_bf16(a0[kt], b, acc0, 0, 0, 0);
            acc1 = __builtin_amdgcn_mfma_f32_16x16x32_bf16(a1[kt], b, acc1, 0, 0, 0);
        }
        const float bv = bias[n];
        #pragma unroll
        for (int i = 0; i < 4; ++i) {
            const int m0 = rbase + lg * 4 + i;
            if (m0 < N_NODES)      out[m0 * D + n] = acc0[i] + bv;
            const int m1 = m0 + 16;
            if (m1 < N_NODES)      out[m1 * D + n] = acc1[i] + bv;
        }
    }
}

extern "C" void kernel_launch(void* const* d_in, const int* in_sizes, int n_in,
                              void* d_out, int out_size, void* d_ws, size_t ws_size,
                              hipStream_t stream) {
    const float* x     = (const float*)d_in[0];
    const int* ei      = (const int*)d_in[1];
    const float* Ws    = (const float*)d_in[2];
    const float* Wn    = (const float*)d_in[3];
    const float* bias  = (const float*)d_in[4];
    float* out = (float*)d_out;

    prep<<<6379, 256, 0, stream>>>(x, Ws, Wn);
    bin_pass<<<(N_EDGES + EPB - 1) / EPB, 256, 0, stream>>>(ei);  // 391 blocks
    bucket_build<<<NBUCK, 256, 0, stream>>>();                    // 391 blocks
    sag_gather<<<(N_NODES * 64) / 256, 256, 0, stream>>>();           // 25000 blocks
    sag_gemm_mfma<<<(N_NODES + 127) / 128, 256, 0, stream>>>(bias, out); // 782 blocks
}